// Round 1
// baseline (3432.608 us; speedup 1.0000x reference)
//
#include <hip/hip_runtime.h>

#define T_STEPS 60
#define WARMUP  29
#define HID     32

__device__ __forceinline__ float fexp2(float x) { return __builtin_amdgcn_exp2f(x); }
__device__ __forceinline__ float frcp(float x)  { return __builtin_amdgcn_rcpf(x); }
// sigmoid(x) = 1/(1+2^(-x*log2e))
__device__ __forceinline__ float sigmoid_f(float x) {
    return frcp(1.0f + fexp2(-1.4426950408889634f * x));
}
// tanh(x) = 1 - 2/(2^(2x*log2e)+1)   (saturates correctly at +-inf)
__device__ __forceinline__ float tanh_f(float x) {
    float e = fexp2(2.8853900817779268f * x);
    return 1.0f - 2.0f * frcp(e + 1.0f);
}

__global__ __launch_bounds__(256) void gru_kernel(
    const float* __restrict__ input, const float* __restrict__ w_ih,
    const float* __restrict__ w_hh,  const float* __restrict__ b_ih,
    const float* __restrict__ b_hh,  const float* __restrict__ w_lin,
    const float* __restrict__ b_lin, float* __restrict__ out,
    float* __restrict__ h28out)
{
    const int b = blockIdx.x * blockDim.x + threadIdx.x;
    const float* xin   = input + (size_t)b * (4 * T_STEPS);
    float*       obase = out   + (size_t)b * (4 * T_STEPS);

    float h[HID];
#pragma unroll
    for (int j = 0; j < HID; ++j) h[j] = 0.0f;
    float prev[4] = {0.0f, 0.0f, 0.0f, 0.0f};

    for (int t = 0; t < T_STEPS; ++t) {
        float inp[4];
        if (t < WARMUP) {
#pragma unroll
            for (int c = 0; c < 4; ++c) inp[c] = xin[c * T_STEPS + t];
        } else {
#pragma unroll
            for (int c = 0; c < 4; ++c) inp[c] = prev[c];
        }

        float hn[HID];
#pragma unroll
        for (int j = 0; j < HID; ++j) {
            // input-side gates (K=4)
            float ir = b_ih[j], iz = b_ih[HID + j], inn = b_ih[2 * HID + j];
#pragma unroll
            for (int k = 0; k < 4; ++k) {
                ir  += w_ih[j * 4 + k]             * inp[k];
                iz  += w_ih[(HID + j) * 4 + k]     * inp[k];
                inn += w_ih[(2 * HID + j) * 4 + k] * inp[k];
            }
            // hidden-side gates (K=32)
            float hr = b_hh[j], hz = b_hh[HID + j], hnn = b_hh[2 * HID + j];
#pragma unroll
            for (int k = 0; k < HID; ++k) {
                hr  += w_hh[j * HID + k]             * h[k];
                hz  += w_hh[(HID + j) * HID + k]     * h[k];
                hnn += w_hh[(2 * HID + j) * HID + k] * h[k];
            }
            float r = sigmoid_f(ir + hr);
            float z = sigmoid_f(iz + hz);
            float n = tanh_f(inn + r * hnn);
            hn[j] = (1.0f - z) * n + z * h[j];
        }
#pragma unroll
        for (int j = 0; j < HID; ++j) h[j] = hn[j];

        // out = h @ w_lin^T + b_lin  (also the next step's input after warmup)
#pragma unroll
        for (int m = 0; m < 4; ++m) {
            float o = b_lin[m];
#pragma unroll
            for (int k = 0; k < HID; ++k) o += w_lin[m * HID + k] * h[k];
            prev[m] = o;
            obase[m * T_STEPS + t] = o;
        }

        if (t == WARMUP - 1) {
#pragma unroll
            for (int j = 0; j < HID; ++j) h28out[(size_t)b * HID + j] = h[j];
        }
    }
}

extern "C" void kernel_launch(void* const* d_in, const int* in_sizes, int n_in,
                              void* d_out, int out_size, void* d_ws, size_t ws_size,
                              hipStream_t stream) {
    const float* input = (const float*)d_in[0];
    const float* w_ih  = (const float*)d_in[1];
    const float* w_hh  = (const float*)d_in[2];
    const float* b_ih  = (const float*)d_in[3];
    const float* b_hh  = (const float*)d_in[4];
    const float* w_lin = (const float*)d_in[5];
    const float* b_lin = (const float*)d_in[6];

    const int B = in_sizes[0] / (4 * T_STEPS);
    float* out = (float*)d_out;
    float* h28 = out + (size_t)B * 4 * T_STEPS;

    dim3 grid(B / 256), block(256);
    hipLaunchKernelGGL(gru_kernel, grid, block, 0, stream,
                       input, w_ih, w_hh, b_ih, b_hh, w_lin, b_lin, out, h28);
}

// Round 2
// 2955.903 us; speedup vs baseline: 1.1613x; 1.1613x over previous
//
#include <hip/hip_runtime.h>

#define T_STEPS 60
#define WARMUP  29
#define HID     32

__device__ __forceinline__ float fexp2(float x) { return __builtin_amdgcn_exp2f(x); }
__device__ __forceinline__ float frcp(float x)  { return __builtin_amdgcn_rcpf(x); }
// sigmoid(x) = 1/(1+2^(-x*log2e))
__device__ __forceinline__ float sigmoid_f(float x) {
    return frcp(1.0f + fexp2(-1.4426950408889634f * x));
}
// tanh(x) = 1 - 2/(2^(2x*log2e)+1)
__device__ __forceinline__ float tanh_f(float x) {
    float e = fexp2(2.8853900817779268f * x);
    return 1.0f - 2.0f * frcp(e + 1.0f);
}

// One GRU step + output projection. h updated in place; returns new out in prev[].
__device__ __forceinline__ void gru_step(
    const float inp[4], float h[HID], float prev[4],
    const float* __restrict__ w_ih, const float* __restrict__ w_hh,
    const float* __restrict__ b_ih, const float* __restrict__ b_hh,
    const float* __restrict__ w_lin, const float* __restrict__ b_lin)
{
    float hn[HID];
#pragma unroll
    for (int j = 0; j < HID; ++j) {
        // accumulators seeded with (uniform, scalar-pipe) bias sums
        float gr = b_ih[j]           + b_hh[j];
        float gz = b_ih[HID + j]     + b_hh[HID + j];
        float gn_i = b_ih[2 * HID + j];
        float gn_h = b_hh[2 * HID + j];
#pragma unroll
        for (int k = 0; k < 4; ++k) {
            gr   += w_ih[j * 4 + k]             * inp[k];
            gz   += w_ih[(HID + j) * 4 + k]     * inp[k];
            gn_i += w_ih[(2 * HID + j) * 4 + k] * inp[k];
        }
#pragma unroll
        for (int k = 0; k < HID; ++k) {
            gr   += w_hh[j * HID + k]             * h[k];
            gz   += w_hh[(HID + j) * HID + k]     * h[k];
            gn_h += w_hh[(2 * HID + j) * HID + k] * h[k];
        }
        float r = sigmoid_f(gr);
        float z = sigmoid_f(gz);
        float n = tanh_f(gn_i + r * gn_h);
        hn[j] = n + z * (h[j] - n);   // == (1-z)*n + z*h
    }
#pragma unroll
    for (int j = 0; j < HID; ++j) h[j] = hn[j];

#pragma unroll
    for (int m = 0; m < 4; ++m) {
        float o = b_lin[m];
#pragma unroll
        for (int k = 0; k < HID; ++k) o += w_lin[m * HID + k] * h[k];
        prev[m] = o;
    }
}

__global__ __launch_bounds__(256, 2) void gru_kernel(
    const float* __restrict__ input, const float* __restrict__ w_ih,
    const float* __restrict__ w_hh,  const float* __restrict__ b_ih,
    const float* __restrict__ b_hh,  const float* __restrict__ w_lin,
    const float* __restrict__ b_lin, float* __restrict__ out,
    float* __restrict__ h28out)
{
    const int b = blockIdx.x * blockDim.x + threadIdx.x;
    const float* xin   = input + (size_t)b * (4 * T_STEPS);
    float*       obase = out   + (size_t)b * (4 * T_STEPS);

    float h[HID];
#pragma unroll
    for (int j = 0; j < HID; ++j) h[j] = 0.0f;
    float prev[4];

    // Phase 1: warmup — input comes from global x
    for (int t = 0; t < WARMUP; ++t) {
        float inp[4];
#pragma unroll
        for (int c = 0; c < 4; ++c) inp[c] = xin[c * T_STEPS + t];
        gru_step(inp, h, prev, w_ih, w_hh, b_ih, b_hh, w_lin, b_lin);
#pragma unroll
        for (int m = 0; m < 4; ++m) obase[m * T_STEPS + t] = prev[m];
    }

    // h after step index WARMUP-1 (t==28)
#pragma unroll
    for (int j = 0; j < HID; ++j) h28out[(size_t)b * HID + j] = h[j];

    // Phase 2: feedback — input is previous output
    for (int t = WARMUP; t < T_STEPS; ++t) {
        gru_step(prev, h, prev, w_ih, w_hh, b_ih, b_hh, w_lin, b_lin);
#pragma unroll
        for (int m = 0; m < 4; ++m) obase[m * T_STEPS + t] = prev[m];
    }
}

extern "C" void kernel_launch(void* const* d_in, const int* in_sizes, int n_in,
                              void* d_out, int out_size, void* d_ws, size_t ws_size,
                              hipStream_t stream) {
    const float* input = (const float*)d_in[0];
    const float* w_ih  = (const float*)d_in[1];
    const float* w_hh  = (const float*)d_in[2];
    const float* b_ih  = (const float*)d_in[3];
    const float* b_hh  = (const float*)d_in[4];
    const float* w_lin = (const float*)d_in[5];
    const float* b_lin = (const float*)d_in[6];

    const int B = in_sizes[0] / (4 * T_STEPS);
    float* out = (float*)d_out;
    float* h28 = out + (size_t)B * 4 * T_STEPS;

    dim3 grid(B / 256), block(256);
    hipLaunchKernelGGL(gru_kernel, grid, block, 0, stream,
                       input, w_ih, w_hh, b_ih, b_hh, w_lin, b_lin, out, h28);
}

// Round 3
// 2591.766 us; speedup vs baseline: 1.3244x; 1.1405x over previous
//
#include <hip/hip_runtime.h>

#define T_STEPS 60
#define WARMUP  29
#define HID     32
#define CT      240   // 4 * T_STEPS (flattened channel-time)
#define BT      64    // batch tile for transposes
#define PAD     244   // LDS row pad: 244*4 B = 16-aligned rows, float4-safe

__device__ __forceinline__ float fexp2(float x) { return __builtin_amdgcn_exp2f(x); }
__device__ __forceinline__ float frcp(float x)  { return __builtin_amdgcn_rcpf(x); }
__device__ __forceinline__ float sigmoid_f(float x) {
    return frcp(1.0f + fexp2(-1.4426950408889634f * x));
}
__device__ __forceinline__ float tanh_f(float x) {
    float e = fexp2(2.8853900817779268f * x);
    return 1.0f - 2.0f * frcp(e + 1.0f);
}

// in[B][240] -> xT[240][B]  (both sides coalesced via LDS tile)
__global__ __launch_bounds__(256) void transpose_in(
    const float* __restrict__ in, float* __restrict__ xT, int B)
{
    __shared__ float tile[BT][PAD];
    const int b0 = blockIdx.x * BT;
    const int tid = threadIdx.x;
    const float* src = in + (size_t)b0 * CT;   // 64*240 floats, contiguous
#pragma unroll
    for (int k = 0; k < 15; ++k) {
        int f = tid * 4 + k * 1024;            // f%4==0, 240%4==0 -> no row cross
        float4 v = *(const float4*)(src + f);
        int r = f / CT, c = f % CT;
        *(float4*)&tile[r][c] = v;
    }
    __syncthreads();
    const int bl = tid & 63, q = tid >> 6;     // lane->batch, wave->ct quarter
#pragma unroll 4
    for (int i = 0; i < 60; ++i) {
        int ct = q * 60 + i;
        xT[(size_t)ct * B + b0 + bl] = tile[bl][ct];   // 4B/lane dense
    }
}

// oT[240][B] -> out[B][240]
__global__ __launch_bounds__(256) void transpose_out(
    const float* __restrict__ oT, float* __restrict__ out, int B)
{
    __shared__ float tile[BT][PAD];
    const int b0 = blockIdx.x * BT;
    const int tid = threadIdx.x;
    const int bl = tid & 63, q = tid >> 6;
#pragma unroll 4
    for (int i = 0; i < 60; ++i) {
        int ct = q * 60 + i;
        tile[bl][ct] = oT[(size_t)ct * B + b0 + bl];   // 4B/lane dense
    }
    __syncthreads();
    float* dst = out + (size_t)b0 * CT;
#pragma unroll
    for (int k = 0; k < 15; ++k) {
        int f = tid * 4 + k * 1024;
        int r = f / CT, c = f % CT;
        *(float4*)(dst + f) = *(const float4*)&tile[r][c];
    }
}

// One GRU step + output projection; h updated in place, out in prev[].
__device__ __forceinline__ void gru_step(
    const float inp[4], float h[HID], float prev[4],
    const float* __restrict__ w_ih, const float* __restrict__ w_hh,
    const float* __restrict__ b_ih, const float* __restrict__ b_hh,
    const float* __restrict__ w_lin, const float* __restrict__ b_lin)
{
    float hn[HID];
#pragma unroll
    for (int j = 0; j < HID; ++j) {
        float gr   = b_ih[j]           + b_hh[j];
        float gz   = b_ih[HID + j]     + b_hh[HID + j];
        float gn_i = b_ih[2 * HID + j];
        float gn_h = b_hh[2 * HID + j];
#pragma unroll
        for (int k = 0; k < 4; ++k) {
            gr   += w_ih[j * 4 + k]             * inp[k];
            gz   += w_ih[(HID + j) * 4 + k]     * inp[k];
            gn_i += w_ih[(2 * HID + j) * 4 + k] * inp[k];
        }
#pragma unroll
        for (int k = 0; k < HID; ++k) {
            gr   += w_hh[j * HID + k]             * h[k];
            gz   += w_hh[(HID + j) * HID + k]     * h[k];
            gn_h += w_hh[(2 * HID + j) * HID + k] * h[k];
        }
        float r = sigmoid_f(gr);
        float z = sigmoid_f(gz);
        float n = tanh_f(gn_i + r * gn_h);
        hn[j] = n + z * (h[j] - n);
    }
#pragma unroll
    for (int j = 0; j < HID; ++j) h[j] = hn[j];

#pragma unroll
    for (int m = 0; m < 4; ++m) {
        float o = b_lin[m];
#pragma unroll
        for (int k = 0; k < HID; ++k) o += w_lin[m * HID + k] * h[k];
        prev[m] = o;
    }
}

// xo = xT buffer [240][B]; outputs written in place (slot [c][t] consumed at
// step t before being overwritten at step t; later steps never re-read it).
__global__ __launch_bounds__(256, 2) void gru_main(
    float* xo,
    const float* __restrict__ w_ih,  const float* __restrict__ w_hh,
    const float* __restrict__ b_ih,  const float* __restrict__ b_hh,
    const float* __restrict__ w_lin, const float* __restrict__ b_lin,
    float* __restrict__ h28out, int B)
{
    const int b = blockIdx.x * blockDim.x + threadIdx.x;

    float h[HID];
#pragma unroll
    for (int j = 0; j < HID; ++j) h[j] = 0.0f;
    float prev[4];

    // Phase 1: warmup — input from xT, dense lane-consecutive loads
    for (int t = 0; t < WARMUP; ++t) {
        float inp[4];
#pragma unroll
        for (int c = 0; c < 4; ++c) inp[c] = xo[(size_t)(c * T_STEPS + t) * B + b];
        gru_step(inp, h, prev, w_ih, w_hh, b_ih, b_hh, w_lin, b_lin);
#pragma unroll
        for (int m = 0; m < 4; ++m) xo[(size_t)(m * T_STEPS + t) * B + b] = prev[m];
    }

    // h after step t==28
    {
        float4* dst = (float4*)(h28out + (size_t)b * HID);
#pragma unroll
        for (int j = 0; j < 8; ++j)
            dst[j] = make_float4(h[4 * j], h[4 * j + 1], h[4 * j + 2], h[4 * j + 3]);
    }

    // Phase 2: feedback
    for (int t = WARMUP; t < T_STEPS; ++t) {
        gru_step(prev, h, prev, w_ih, w_hh, b_ih, b_hh, w_lin, b_lin);
#pragma unroll
        for (int m = 0; m < 4; ++m) xo[(size_t)(m * T_STEPS + t) * B + b] = prev[m];
    }
}

extern "C" void kernel_launch(void* const* d_in, const int* in_sizes, int n_in,
                              void* d_out, int out_size, void* d_ws, size_t ws_size,
                              hipStream_t stream) {
    const float* input = (const float*)d_in[0];
    const float* w_ih  = (const float*)d_in[1];
    const float* w_hh  = (const float*)d_in[2];
    const float* b_ih  = (const float*)d_in[3];
    const float* b_hh  = (const float*)d_in[4];
    const float* w_lin = (const float*)d_in[5];
    const float* b_lin = (const float*)d_in[6];

    const int B = in_sizes[0] / CT;          // 131072
    float* out = (float*)d_out;              // [B][240]
    float* h28 = out + (size_t)B * CT;       // [B][32]
    float* xo  = (float*)d_ws;               // [240][B] transposed x / out buffer

    hipLaunchKernelGGL(transpose_in, dim3(B / BT), dim3(256), 0, stream,
                       input, xo, B);
    hipLaunchKernelGGL(gru_main, dim3(B / 256), dim3(256), 0, stream,
                       xo, w_ih, w_hh, b_ih, b_hh, w_lin, b_lin, h28, B);
    hipLaunchKernelGGL(transpose_out, dim3(B / BT), dim3(256), 0, stream,
                       xo, out, B);
}